// Round 4
// baseline (384.346 us; speedup 1.0000x reference)
//
#include <hip/hip_runtime.h>

#define HIDDEN 128
#define SCAN_B 1024

typedef float v2f __attribute__((ext_vector_type(2)));
__device__ __forceinline__ v2f v2s(float a) { v2f r; r.x = a; r.y = a; return r; }

// ================= CSR build (per call; no fp atomics anywhere) =============
// k_hist also records each edge's rank within its dst bucket (atomic return),
// so k_fill needs no second atomic pass.
__global__ __launch_bounds__(256)
void k_hist(const int* __restrict__ dst, int* __restrict__ cnt,
            int* __restrict__ rank, int E) {
    int e = blockIdx.x * 256 + threadIdx.x;
    if (e < E) rank[e] = atomicAdd(&cnt[dst[e]], 1);
}

// block-level inclusive scan -> exclusive offsets + block sums
__global__ __launch_bounds__(SCAN_B)
void k_scan1(const int* __restrict__ cnt, int* __restrict__ offs,
             int* __restrict__ bsum, int N) {
    __shared__ int sm[SCAN_B];
    int g = blockIdx.x * SCAN_B + threadIdx.x;
    int v = (g < N) ? cnt[g] : 0;
    int acc = v;
    sm[threadIdx.x] = v;
    __syncthreads();
    for (int d = 1; d < SCAN_B; d <<= 1) {
        int t = (threadIdx.x >= d) ? sm[threadIdx.x - d] : 0;
        __syncthreads();
        acc += t;
        sm[threadIdx.x] = acc;
        __syncthreads();
    }
    if (g < N) offs[g] = acc - v;                 // exclusive
    if (threadIdx.x == SCAN_B - 1) bsum[blockIdx.x] = acc;
}

__global__ __launch_bounds__(SCAN_B)
void k_scan2(int* __restrict__ bsum, int nb) {
    __shared__ int sm[SCAN_B];
    int v = (threadIdx.x < nb) ? bsum[threadIdx.x] : 0;
    int acc = v;
    sm[threadIdx.x] = v;
    __syncthreads();
    for (int d = 1; d < SCAN_B; d <<= 1) {
        int t = (threadIdx.x >= d) ? sm[threadIdx.x - d] : 0;
        __syncthreads();
        acc += t;
        sm[threadIdx.x] = acc;
        __syncthreads();
    }
    if (threadIdx.x < nb) bsum[threadIdx.x] = acc - v;   // exclusive
}

__global__ __launch_bounds__(SCAN_B)
void k_scan3(int* __restrict__ offs, const int* __restrict__ bsum, int N) {
    int g = blockIdx.x * SCAN_B + threadIdx.x;
    if (g < N) offs[g] += bsum[blockIdx.x];
}

// Scatter edges into CSR order. One 8B packed store per edge (src, w).
__global__ __launch_bounds__(256)
void k_fill(const int* __restrict__ src, const int* __restrict__ dst,
            const float* __restrict__ ew, const int* __restrict__ offs,
            const int* __restrict__ rank, int2* __restrict__ cpack, int E) {
    int e = blockIdx.x * 256 + threadIdx.x;
    if (e >= E) return;
    int d = dst[e];
    int slot = offs[d] + rank[e];
    int2 p;
    p.x = src[e];
    p.y = __float_as_int(ew[e]);
    cpack[slot] = p;
}

// degree from offs-diff (offs has N entries; last degree uses E)
__device__ __forceinline__ int end_of(const int* offs, int i, int N, int E) {
    return (i + 1 < N) ? offs[i + 1] : E;
}

// ================= layer 1: gather 2ch into aggr1 ===========================
__global__ __launch_bounds__(256)
void k_gather2(const int* __restrict__ offs, const int2* __restrict__ cpack,
               const float* __restrict__ x, float2* __restrict__ aggr1,
               int N, int E) {
    int i = blockIdx.x * 256 + threadIdx.x;
    if (i >= N) return;
    int start = offs[i], end = end_of(offs, i, N, E);
    float a0 = 0.f, a1 = 0.f;
    for (int j = start; j < end; ++j) {
        int2  p = cpack[j];
        int   s = p.x;
        float w = __int_as_float(p.y);
        float2 xv = *reinterpret_cast<const float2*>(x + (size_t)s * 2);
        a0 = fmaf(w, xv.x, a0);
        a1 = fmaf(w, xv.y, a1);
    }
    aggr1[i] = make_float2(a0, a1);
}

// ================= fused layer-2 aggregation + layer-1 node update ==========
// Per edge, recompute h1[src] from 4 scalars (aggr1[src], x[src]) — both
// arrays are 800KB, L2-resident. Wave per dst node; lane l owns channels
// (2l, 2l+1) as ONE packed <2 x float> (v_pk_fma_f32 on gfx950).
// Edge scalars read at wave-uniform addresses (HW broadcast — no shfl
// staging); 4-edge unroll with hoisted loads for memory-level parallelism.
// Epilogue writes the wave's own h1 row (k_node1 fused away).
__global__ __launch_bounds__(256)
void k_gatherfused(const int* __restrict__ offs, const int2* __restrict__ cpack,
                   const float2* __restrict__ aggr1, const float* __restrict__ x,
                   const float* __restrict__ W1rel, const float* __restrict__ b1,
                   const float* __restrict__ W1root,
                   float* __restrict__ h, float* __restrict__ aggr,
                   int N, int E) {
    int wv   = (blockIdx.x * 256 + threadIdx.x) >> 6;
    int lane = threadIdx.x & 63;
    if (wv >= N) return;

    const int c0 = lane * 2;
    const v2f WR0 = *reinterpret_cast<const v2f*>(W1rel  + c0);
    const v2f WR1 = *reinterpret_cast<const v2f*>(W1rel  + HIDDEN + c0);
    const v2f WO0 = *reinterpret_cast<const v2f*>(W1root + c0);
    const v2f WO1 = *reinterpret_cast<const v2f*>(W1root + HIDDEN + c0);
    const v2f B   = *reinterpret_cast<const v2f*>(b1 + c0);

    int start = offs[wv], end = end_of(offs, wv, N, E);
    v2f acc = {0.f, 0.f};

    int j = start;
    for (; j + 4 <= end; j += 4) {
        // wave-uniform loads (HW broadcast), hoisted for ILP
        int2 p0 = cpack[j + 0];
        int2 p1 = cpack[j + 1];
        int2 p2 = cpack[j + 2];
        int2 p3 = cpack[j + 3];
        float2 A0 = aggr1[p0.x];
        float2 X0 = *reinterpret_cast<const float2*>(x + (size_t)p0.x * 2);
        float2 A1 = aggr1[p1.x];
        float2 X1 = *reinterpret_cast<const float2*>(x + (size_t)p1.x * 2);
        float2 A2 = aggr1[p2.x];
        float2 X2 = *reinterpret_cast<const float2*>(x + (size_t)p2.x * 2);
        float2 A3 = aggr1[p3.x];
        float2 X3 = *reinterpret_cast<const float2*>(x + (size_t)p3.x * 2);

        v2f t0 = B + v2s(A0.x) * WR0 + v2s(A0.y) * WR1
                   + v2s(X0.x) * WO0 + v2s(X0.y) * WO1;
        v2f t1 = B + v2s(A1.x) * WR0 + v2s(A1.y) * WR1
                   + v2s(X1.x) * WO0 + v2s(X1.y) * WO1;
        v2f t2 = B + v2s(A2.x) * WR0 + v2s(A2.y) * WR1
                   + v2s(X2.x) * WO0 + v2s(X2.y) * WO1;
        v2f t3 = B + v2s(A3.x) * WR0 + v2s(A3.y) * WR1
                   + v2s(X3.x) * WO0 + v2s(X3.y) * WO1;
        t0.x = fmaxf(t0.x, 0.f); t0.y = fmaxf(t0.y, 0.f);
        t1.x = fmaxf(t1.x, 0.f); t1.y = fmaxf(t1.y, 0.f);
        t2.x = fmaxf(t2.x, 0.f); t2.y = fmaxf(t2.y, 0.f);
        t3.x = fmaxf(t3.x, 0.f); t3.y = fmaxf(t3.y, 0.f);
        acc = acc + v2s(__int_as_float(p0.y)) * t0;
        acc = acc + v2s(__int_as_float(p1.y)) * t1;
        acc = acc + v2s(__int_as_float(p2.y)) * t2;
        acc = acc + v2s(__int_as_float(p3.y)) * t3;
    }
    for (; j < end; ++j) {     // tail (<=3 edges)
        int2 p0 = cpack[j];
        float2 A0 = aggr1[p0.x];
        float2 X0 = *reinterpret_cast<const float2*>(x + (size_t)p0.x * 2);
        v2f t0 = B + v2s(A0.x) * WR0 + v2s(A0.y) * WR1
                   + v2s(X0.x) * WO0 + v2s(X0.y) * WO1;
        t0.x = fmaxf(t0.x, 0.f); t0.y = fmaxf(t0.y, 0.f);
        acc = acc + v2s(__int_as_float(p0.y)) * t0;
    }

    *reinterpret_cast<v2f*>(aggr + (size_t)wv * HIDDEN + c0) = acc;

    // fused k_node1: this wave's own h1 row
    {
        float2 a  = aggr1[wv];
        float2 xv = *reinterpret_cast<const float2*>(x + (size_t)wv * 2);
        v2f t = B + v2s(a.x) * WR0 + v2s(a.y) * WR1
                  + v2s(xv.x) * WO0 + v2s(xv.y) * WO1;
        t.x = fmaxf(t.x, 0.f); t.y = fmaxf(t.y, 0.f);
        *reinterpret_cast<v2f*>(h + (size_t)wv * HIDDEN + c0) = t;
    }
}

// ================= layer 2 node update: LDS-tiled fp32 GEMM =================
// h2 = relu([aggr | h] @ [W2rel ; W2root] + b2), written IN PLACE over h.
#define BM2 64
#define XS_STRIDE 68   // 64 + 4 pad: float4 alignment + bank spread

__global__ __launch_bounds__(256)
void k_node2(const float* __restrict__ aggr, float* __restrict__ h,
             const float* __restrict__ Wrel, const float* __restrict__ b,
             const float* __restrict__ Wroot, int N) {
    __shared__ float Xs[BM2 * XS_STRIDE];     // 64 x 64 input tile (+pad)
    __shared__ float Ws[64 * HIDDEN];         // 64 x 128 weight tile

    const int tid = threadIdx.x;
    const int ci  = tid & 15;                 // channel group: cols ci*4, 64+ci*4
    const int ri  = tid >> 4;                 // node group: rows ri*4 .. ri*4+3
    const int nb  = blockIdx.x * BM2;

    float acc[4][8];
    {
        float4 b0 = *reinterpret_cast<const float4*>(b + ci * 4);
        float4 b1 = *reinterpret_cast<const float4*>(b + 64 + ci * 4);
#pragma unroll
        for (int m = 0; m < 4; ++m) {
            acc[m][0] = b0.x; acc[m][1] = b0.y; acc[m][2] = b0.z; acc[m][3] = b0.w;
            acc[m][4] = b1.x; acc[m][5] = b1.y; acc[m][6] = b1.z; acc[m][7] = b1.w;
        }
    }

    for (int t = 0; t < 4; ++t) {
        const float* Xsrc = (t < 2) ? aggr : (const float*)h;
        const float* Wsrc = (t < 2) ? Wrel : Wroot;
        const int kc = (t & 1) * 64;

        __syncthreads();
#pragma unroll
        for (int q = 0; q < 4; ++q) {
            int idx = q * 256 + tid;
            int row = idx >> 4;
            int c4  = (idx & 15) * 4;
            int gr  = nb + row; if (gr >= N) gr = N - 1;
            float4 v = *reinterpret_cast<const float4*>(Xsrc + (size_t)gr * HIDDEN + kc + c4);
            *reinterpret_cast<float4*>(&Xs[row * XS_STRIDE + c4]) = v;
        }
#pragma unroll
        for (int q = 0; q < 8; ++q) {
            int idx = q * 256 + tid;
            int row = idx >> 5;
            int c4  = (idx & 31) * 4;
            float4 v = *reinterpret_cast<const float4*>(Wsrc + (size_t)(kc + row) * HIDDEN + c4);
            *reinterpret_cast<float4*>(&Ws[row * HIDDEN + c4]) = v;
        }
        __syncthreads();

#pragma unroll
        for (int kk = 0; kk < 64; kk += 4) {
            float4 xr[4];
#pragma unroll
            for (int m = 0; m < 4; ++m)
                xr[m] = *reinterpret_cast<const float4*>(&Xs[(ri * 4 + m) * XS_STRIDE + kk]);
#pragma unroll
            for (int j = 0; j < 4; ++j) {
                float4 w0 = *reinterpret_cast<const float4*>(&Ws[(kk + j) * HIDDEN + ci * 4]);
                float4 w1 = *reinterpret_cast<const float4*>(&Ws[(kk + j) * HIDDEN + 64 + ci * 4]);
#pragma unroll
                for (int m = 0; m < 4; ++m) {
                    float xm = (j == 0) ? xr[m].x : (j == 1) ? xr[m].y
                             : (j == 2) ? xr[m].z : xr[m].w;
                    acc[m][0] = fmaf(xm, w0.x, acc[m][0]);
                    acc[m][1] = fmaf(xm, w0.y, acc[m][1]);
                    acc[m][2] = fmaf(xm, w0.z, acc[m][2]);
                    acc[m][3] = fmaf(xm, w0.w, acc[m][3]);
                    acc[m][4] = fmaf(xm, w1.x, acc[m][4]);
                    acc[m][5] = fmaf(xm, w1.y, acc[m][5]);
                    acc[m][6] = fmaf(xm, w1.z, acc[m][6]);
                    acc[m][7] = fmaf(xm, w1.w, acc[m][7]);
                }
            }
        }
    }

#pragma unroll
    for (int m = 0; m < 4; ++m) {
        int node = nb + ri * 4 + m;
        if (node < N) {
            float4 o0, o1;
            o0.x = fmaxf(acc[m][0], 0.f); o0.y = fmaxf(acc[m][1], 0.f);
            o0.z = fmaxf(acc[m][2], 0.f); o0.w = fmaxf(acc[m][3], 0.f);
            o1.x = fmaxf(acc[m][4], 0.f); o1.y = fmaxf(acc[m][5], 0.f);
            o1.z = fmaxf(acc[m][6], 0.f); o1.w = fmaxf(acc[m][7], 0.f);
            float* o = h + (size_t)node * HIDDEN;
            *reinterpret_cast<float4*>(o + ci * 4)      = o0;
            *reinterpret_cast<float4*>(o + 64 + ci * 4) = o1;
        }
    }
}

// ================= layer 3: project to 3ch, then gather =====================
__global__ __launch_bounds__(256)
void k_node3(const float* __restrict__ h2,
             const float* __restrict__ Wrel, const float* __restrict__ b,
             const float* __restrict__ Wroot,
             float* __restrict__ z, float* __restrict__ out, int N) {
    int i = blockIdx.x * 256 + threadIdx.x;
    if (i >= N) return;
    float zr[3] = {0.f, 0.f, 0.f};
    float zo[3] = {b[0], b[1], b[2]};
    const float4* h4 = reinterpret_cast<const float4*>(h2 + (size_t)i * HIDDEN);
    for (int kk = 0; kk < HIDDEN / 4; ++kk) {
        float4 hv = h4[kk];
#pragma unroll
        for (int j = 0; j < 4; ++j) {
            int k = kk * 4 + j;
            float hj = (j == 0) ? hv.x : (j == 1) ? hv.y : (j == 2) ? hv.z : hv.w;
#pragma unroll
            for (int c = 0; c < 3; ++c) {
                zr[c] = fmaf(hj, Wrel [k * 3 + c], zr[c]);
                zo[c] = fmaf(hj, Wroot[k * 3 + c], zo[c]);
            }
        }
    }
    z[(size_t)i * 3 + 0] = zr[0]; z[(size_t)i * 3 + 1] = zr[1]; z[(size_t)i * 3 + 2] = zr[2];
    out[(size_t)i * 3 + 0] = zo[0]; out[(size_t)i * 3 + 1] = zo[1]; out[(size_t)i * 3 + 2] = zo[2];
}

__global__ __launch_bounds__(256)
void k_gather3(const int* __restrict__ offs, const int2* __restrict__ cpack,
               const float* __restrict__ z, float* __restrict__ out,
               int N, int E) {
    int i = blockIdx.x * 256 + threadIdx.x;
    if (i >= N) return;
    int start = offs[i], end = end_of(offs, i, N, E);
    float a0 = 0.f, a1 = 0.f, a2 = 0.f;
    for (int j = start; j < end; ++j) {
        int2  p = cpack[j];
        int   s = p.x;
        float w = __int_as_float(p.y);
        const float* zp = z + (size_t)s * 3;
        a0 = fmaf(w, zp[0], a0);
        a1 = fmaf(w, zp[1], a1);
        a2 = fmaf(w, zp[2], a2);
    }
    out[(size_t)i * 3 + 0] += a0;
    out[(size_t)i * 3 + 1] += a1;
    out[(size_t)i * 3 + 2] += a2;
}

extern "C" void kernel_launch(void* const* d_in, const int* in_sizes, int n_in,
                              void* d_out, int out_size, void* d_ws, size_t ws_size,
                              hipStream_t stream) {
    const float* x      = (const float*)d_in[0];
    const int*   ei     = (const int*)  d_in[1];
    const float* ew     = (const float*)d_in[2];
    const float* W1rel  = (const float*)d_in[4];
    const float* b1     = (const float*)d_in[5];
    const float* W1root = (const float*)d_in[6];
    const float* W2rel  = (const float*)d_in[7];
    const float* b2     = (const float*)d_in[8];
    const float* W2root = (const float*)d_in[9];
    const float* W3rel  = (const float*)d_in[10];
    const float* b3     = (const float*)d_in[11];
    const float* W3root = (const float*)d_in[12];
    float* out = (float*)d_out;

    const int N = in_sizes[0] / 2;
    const int E = in_sizes[2];
    const int* src = ei;
    const int* dst = ei + E;

    // -------- workspace layout --------
    // h     : N*128 f32   (h1, overwritten in place by h2; front E ints alias
    //         rank during CSR build — rank dead before gatherfused writes h)
    // aggr  : N*128 f32   (layer-2 aggregation; front N*3 reused for z)
    // offs  : N int | bsum : SCAN_B int
    // cpack : E int2      (front N ints alias cnt — cnt dead before k_fill)
    // aggr1 : N float2    (layer-1 aggregation, L2-resident gather target)
    float* h    = (float*)d_ws;
    float* aggr = h + (size_t)N * HIDDEN;
    int*   offs = (int*)(aggr + (size_t)N * HIDDEN);
    int*   bsum = offs + N;
    size_t cpo  = (size_t)(bsum + SCAN_B - (int*)d_ws);
    cpo = (cpo + 1) & ~(size_t)1;          // 8B alignment
    int2*   cpack = (int2*)((int*)d_ws + cpo);
    float2* aggr1 = (float2*)(cpack + E);
    int* cnt  = (int*)cpack;               // alias: dead before k_fill writes cpack
    int* rank = (int*)h;                   // alias: dead before gatherfused writes h

    const int nbScan = (N + SCAN_B - 1) / SCAN_B;

    // -------- CSR build --------
    hipMemsetAsync(cnt, 0, (size_t)N * sizeof(int), stream);
    k_hist <<<(E + 255) / 256, 256, 0, stream>>>(dst, cnt, rank, E);
    k_scan1<<<nbScan, SCAN_B, 0, stream>>>(cnt, offs, bsum, N);
    k_scan2<<<1, SCAN_B, 0, stream>>>(bsum, nbScan);
    k_scan3<<<nbScan, SCAN_B, 0, stream>>>(offs, bsum, N);
    k_fill <<<(E + 255) / 256, 256, 0, stream>>>(src, dst, ew, offs, rank, cpack, E);

    // -------- layer 1 aggregation (2ch) --------
    k_gather2<<<(N + 255) / 256, 256, 0, stream>>>(offs, cpack, x, aggr1, N, E);

    // -------- fused layer-2 aggregation + layer-1 node update --------
    {
        long long threads = (long long)N * 64;
        k_gatherfused<<<(int)((threads + 255) / 256), 256, 0, stream>>>(
            offs, cpack, aggr1, x, W1rel, b1, W1root, h, aggr, N, E);
    }

    // -------- layer 2 node update --------
    k_node2<<<(N + BM2 - 1) / BM2, 256, 0, stream>>>(aggr, h, W2rel, b2, W2root, N);

    // -------- layer 3 --------
    float* z = aggr;   // aggr dead after node2; reuse front N*3 for z
    k_node3  <<<(N + 255) / 256, 256, 0, stream>>>(h, W3rel, b3, W3root, z, out, N);
    k_gather3<<<(N + 255) / 256, 256, 0, stream>>>(offs, cpack, z, out, N, E);
}

// Round 5
// 323.480 us; speedup vs baseline: 1.1882x; 1.1882x over previous
//
#include <hip/hip_runtime.h>

#define HIDDEN 128
#define SCAN_B 1024

typedef float v2f __attribute__((ext_vector_type(2)));
__device__ __forceinline__ v2f v2s(float a) { v2f r; r.x = a; r.y = a; return r; }

// ================= CSR build (per call; no fp atomics anywhere) =============
// k_hist also records each edge's rank within its dst bucket (atomic return),
// so k_fill needs no second atomic pass.
__global__ __launch_bounds__(256)
void k_hist(const int* __restrict__ dst, int* __restrict__ cnt,
            int* __restrict__ rank, int E) {
    int e = blockIdx.x * 256 + threadIdx.x;
    if (e < E) rank[e] = atomicAdd(&cnt[dst[e]], 1);
}

// block-level inclusive scan -> exclusive offsets + block sums
__global__ __launch_bounds__(SCAN_B)
void k_scan1(const int* __restrict__ cnt, int* __restrict__ offs,
             int* __restrict__ bsum, int N) {
    __shared__ int sm[SCAN_B];
    int g = blockIdx.x * SCAN_B + threadIdx.x;
    int v = (g < N) ? cnt[g] : 0;
    int acc = v;
    sm[threadIdx.x] = v;
    __syncthreads();
    for (int d = 1; d < SCAN_B; d <<= 1) {
        int t = (threadIdx.x >= d) ? sm[threadIdx.x - d] : 0;
        __syncthreads();
        acc += t;
        sm[threadIdx.x] = acc;
        __syncthreads();
    }
    if (g < N) offs[g] = acc - v;                 // exclusive
    if (threadIdx.x == SCAN_B - 1) bsum[blockIdx.x] = acc;
}

__global__ __launch_bounds__(SCAN_B)
void k_scan2(int* __restrict__ bsum, int nb) {
    __shared__ int sm[SCAN_B];
    int v = (threadIdx.x < nb) ? bsum[threadIdx.x] : 0;
    int acc = v;
    sm[threadIdx.x] = v;
    __syncthreads();
    for (int d = 1; d < SCAN_B; d <<= 1) {
        int t = (threadIdx.x >= d) ? sm[threadIdx.x - d] : 0;
        __syncthreads();
        acc += t;
        sm[threadIdx.x] = acc;
        __syncthreads();
    }
    if (threadIdx.x < nb) bsum[threadIdx.x] = acc - v;   // exclusive
}

__global__ __launch_bounds__(SCAN_B)
void k_scan3(int* __restrict__ offs, const int* __restrict__ bsum, int N) {
    int g = blockIdx.x * SCAN_B + threadIdx.x;
    if (g < N) offs[g] += bsum[blockIdx.x];
}

// Scatter edges into CSR order. One 8B packed store per edge (src, w).
__global__ __launch_bounds__(256)
void k_fill(const int* __restrict__ src, const int* __restrict__ dst,
            const float* __restrict__ ew, const int* __restrict__ offs,
            const int* __restrict__ rank, int2* __restrict__ cpack, int E) {
    int e = blockIdx.x * 256 + threadIdx.x;
    if (e >= E) return;
    int d = dst[e];
    int slot = offs[d] + rank[e];
    int2 p;
    p.x = src[e];
    p.y = __float_as_int(ew[e]);
    cpack[slot] = p;
}

// degree from offs-diff (offs has N entries; last degree uses E)
__device__ __forceinline__ int end_of(const int* offs, int i, int N, int E) {
    return (i + 1 < N) ? offs[i + 1] : E;
}

// ================= layer 1: gather 2ch, emit combined y = (a0,a1,x0,x1) ====
// yv is the single L2-resident per-node state the fused kernel gathers.
__global__ __launch_bounds__(256)
void k_gather2(const int* __restrict__ offs, const int2* __restrict__ cpack,
               const float* __restrict__ x, float4* __restrict__ yv,
               int N, int E) {
    int i = blockIdx.x * 256 + threadIdx.x;
    if (i >= N) return;
    int start = offs[i], end = end_of(offs, i, N, E);
    float a0 = 0.f, a1 = 0.f;
    for (int j = start; j < end; ++j) {
        int2  p = cpack[j];
        int   s = p.x;
        float w = __int_as_float(p.y);
        float2 xv = *reinterpret_cast<const float2*>(x + (size_t)s * 2);
        a0 = fmaf(w, xv.x, a0);
        a1 = fmaf(w, xv.y, a1);
    }
    float2 xi = *reinterpret_cast<const float2*>(x + (size_t)i * 2);
    yv[i] = make_float4(a0, a1, xi.x, xi.y);
}

// ================= fused layer-2 aggregation + layer-1 node update ==========
// Per edge, recompute h1[src] from yv[src] = (aggr1, x) — 1.6MB, L2-resident.
// Wave per dst node; lane l owns channels (2l,2l+1) as one packed <2 x float>.
// Per-lane STAGING (one coalesced 512B load per 64 edges) + shfl broadcast
// (R3 structure — R4's broadcast-load rewrite regressed), then 4-edge unroll
// with hoisted independent yv loads for MLP. Epilogue writes the wave's own
// h1 row (k_node1 fused away).
__global__ __launch_bounds__(256)
void k_gatherfused(const int* __restrict__ offs, const int2* __restrict__ cpack,
                   const float4* __restrict__ yv,
                   const float* __restrict__ W1rel, const float* __restrict__ b1,
                   const float* __restrict__ W1root,
                   float* __restrict__ h, float* __restrict__ aggr,
                   int N, int E) {
    int wv   = (blockIdx.x * 256 + threadIdx.x) >> 6;
    int lane = threadIdx.x & 63;
    if (wv >= N) return;

    const int c0 = lane * 2;
    const v2f WR0 = *reinterpret_cast<const v2f*>(W1rel  + c0);
    const v2f WR1 = *reinterpret_cast<const v2f*>(W1rel  + HIDDEN + c0);
    const v2f WO0 = *reinterpret_cast<const v2f*>(W1root + c0);
    const v2f WO1 = *reinterpret_cast<const v2f*>(W1root + HIDDEN + c0);
    const v2f B   = *reinterpret_cast<const v2f*>(b1 + c0);
    const v2f Z   = {0.f, 0.f};

    int start = offs[wv], end = end_of(offs, wv, N, E);
    v2f acc = {0.f, 0.f};

    for (int base = start; base < end; base += 64) {
        int nb = min(64, end - base);
        int sx = 0, wb = 0;
        if (lane < nb) {                       // one coalesced 8B/lane load
            int2 p = cpack[base + lane];
            sx = p.x; wb = p.y;
        }
        int k = 0;
        for (; k + 4 <= nb; k += 4) {
            int s0 = __shfl(sx, k);
            int s1 = __shfl(sx, k + 1);
            int s2 = __shfl(sx, k + 2);
            int s3 = __shfl(sx, k + 3);
            float w0 = __int_as_float(__shfl(wb, k));
            float w1 = __int_as_float(__shfl(wb, k + 1));
            float w2 = __int_as_float(__shfl(wb, k + 2));
            float w3 = __int_as_float(__shfl(wb, k + 3));
            float4 y0 = yv[s0];                // 4 independent L2 loads in flight
            float4 y1 = yv[s1];
            float4 y2 = yv[s2];
            float4 y3 = yv[s3];

            v2f t0 = B + v2s(y0.x) * WR0 + v2s(y0.y) * WR1
                       + v2s(y0.z) * WO0 + v2s(y0.w) * WO1;
            v2f t1 = B + v2s(y1.x) * WR0 + v2s(y1.y) * WR1
                       + v2s(y1.z) * WO0 + v2s(y1.w) * WO1;
            v2f t2 = B + v2s(y2.x) * WR0 + v2s(y2.y) * WR1
                       + v2s(y2.z) * WO0 + v2s(y2.w) * WO1;
            v2f t3 = B + v2s(y3.x) * WR0 + v2s(y3.y) * WR1
                       + v2s(y3.z) * WO0 + v2s(y3.w) * WO1;
            t0 = __builtin_elementwise_max(t0, Z);
            t1 = __builtin_elementwise_max(t1, Z);
            t2 = __builtin_elementwise_max(t2, Z);
            t3 = __builtin_elementwise_max(t3, Z);
            acc = acc + v2s(w0) * t0;
            acc = acc + v2s(w1) * t1;
            acc = acc + v2s(w2) * t2;
            acc = acc + v2s(w3) * t3;
        }
        for (; k < nb; ++k) {                  // tail (<=3 edges)
            int   s0 = __shfl(sx, k);
            float w0 = __int_as_float(__shfl(wb, k));
            float4 y0 = yv[s0];
            v2f t0 = B + v2s(y0.x) * WR0 + v2s(y0.y) * WR1
                       + v2s(y0.z) * WO0 + v2s(y0.w) * WO1;
            t0 = __builtin_elementwise_max(t0, Z);
            acc = acc + v2s(w0) * t0;
        }
    }

    *reinterpret_cast<v2f*>(aggr + (size_t)wv * HIDDEN + c0) = acc;

    // fused k_node1: this wave's own h1 row
    {
        float4 y = yv[wv];
        v2f t = B + v2s(y.x) * WR0 + v2s(y.y) * WR1
                  + v2s(y.z) * WO0 + v2s(y.w) * WO1;
        t = __builtin_elementwise_max(t, Z);
        *reinterpret_cast<v2f*>(h + (size_t)wv * HIDDEN + c0) = t;
    }
}

// ================= layer 2 node update: LDS-tiled fp32 GEMM =================
// h2 = relu([aggr | h] @ [W2rel ; W2root] + b2), written IN PLACE over h.
#define BM2 64
#define XS_STRIDE 68   // 64 + 4 pad: float4 alignment + bank spread

__global__ __launch_bounds__(256)
void k_node2(const float* __restrict__ aggr, float* __restrict__ h,
             const float* __restrict__ Wrel, const float* __restrict__ b,
             const float* __restrict__ Wroot, int N) {
    __shared__ float Xs[BM2 * XS_STRIDE];     // 64 x 64 input tile (+pad)
    __shared__ float Ws[64 * HIDDEN];         // 64 x 128 weight tile

    const int tid = threadIdx.x;
    const int ci  = tid & 15;                 // channel group: cols ci*4, 64+ci*4
    const int ri  = tid >> 4;                 // node group: rows ri*4 .. ri*4+3
    const int nb  = blockIdx.x * BM2;

    float acc[4][8];
    {
        float4 b0 = *reinterpret_cast<const float4*>(b + ci * 4);
        float4 b1 = *reinterpret_cast<const float4*>(b + 64 + ci * 4);
#pragma unroll
        for (int m = 0; m < 4; ++m) {
            acc[m][0] = b0.x; acc[m][1] = b0.y; acc[m][2] = b0.z; acc[m][3] = b0.w;
            acc[m][4] = b1.x; acc[m][5] = b1.y; acc[m][6] = b1.z; acc[m][7] = b1.w;
        }
    }

    for (int t = 0; t < 4; ++t) {
        const float* Xsrc = (t < 2) ? aggr : (const float*)h;
        const float* Wsrc = (t < 2) ? Wrel : Wroot;
        const int kc = (t & 1) * 64;

        __syncthreads();
#pragma unroll
        for (int q = 0; q < 4; ++q) {
            int idx = q * 256 + tid;
            int row = idx >> 4;
            int c4  = (idx & 15) * 4;
            int gr  = nb + row; if (gr >= N) gr = N - 1;
            float4 v = *reinterpret_cast<const float4*>(Xsrc + (size_t)gr * HIDDEN + kc + c4);
            *reinterpret_cast<float4*>(&Xs[row * XS_STRIDE + c4]) = v;
        }
#pragma unroll
        for (int q = 0; q < 8; ++q) {
            int idx = q * 256 + tid;
            int row = idx >> 5;
            int c4  = (idx & 31) * 4;
            float4 v = *reinterpret_cast<const float4*>(Wsrc + (size_t)(kc + row) * HIDDEN + c4);
            *reinterpret_cast<float4*>(&Ws[row * HIDDEN + c4]) = v;
        }
        __syncthreads();

#pragma unroll
        for (int kk = 0; kk < 64; kk += 4) {
            float4 xr[4];
#pragma unroll
            for (int m = 0; m < 4; ++m)
                xr[m] = *reinterpret_cast<const float4*>(&Xs[(ri * 4 + m) * XS_STRIDE + kk]);
#pragma unroll
            for (int j = 0; j < 4; ++j) {
                float4 w0 = *reinterpret_cast<const float4*>(&Ws[(kk + j) * HIDDEN + ci * 4]);
                float4 w1 = *reinterpret_cast<const float4*>(&Ws[(kk + j) * HIDDEN + 64 + ci * 4]);
#pragma unroll
                for (int m = 0; m < 4; ++m) {
                    float xm = (j == 0) ? xr[m].x : (j == 1) ? xr[m].y
                             : (j == 2) ? xr[m].z : xr[m].w;
                    acc[m][0] = fmaf(xm, w0.x, acc[m][0]);
                    acc[m][1] = fmaf(xm, w0.y, acc[m][1]);
                    acc[m][2] = fmaf(xm, w0.z, acc[m][2]);
                    acc[m][3] = fmaf(xm, w0.w, acc[m][3]);
                    acc[m][4] = fmaf(xm, w1.x, acc[m][4]);
                    acc[m][5] = fmaf(xm, w1.y, acc[m][5]);
                    acc[m][6] = fmaf(xm, w1.z, acc[m][6]);
                    acc[m][7] = fmaf(xm, w1.w, acc[m][7]);
                }
            }
        }
    }

#pragma unroll
    for (int m = 0; m < 4; ++m) {
        int node = nb + ri * 4 + m;
        if (node < N) {
            float4 o0, o1;
            o0.x = fmaxf(acc[m][0], 0.f); o0.y = fmaxf(acc[m][1], 0.f);
            o0.z = fmaxf(acc[m][2], 0.f); o0.w = fmaxf(acc[m][3], 0.f);
            o1.x = fmaxf(acc[m][4], 0.f); o1.y = fmaxf(acc[m][5], 0.f);
            o1.z = fmaxf(acc[m][6], 0.f); o1.w = fmaxf(acc[m][7], 0.f);
            float* o = h + (size_t)node * HIDDEN;
            *reinterpret_cast<float4*>(o + ci * 4)      = o0;
            *reinterpret_cast<float4*>(o + 64 + ci * 4) = o1;
        }
    }
}

// ================= layer 3: project to 3ch, then gather =====================
__global__ __launch_bounds__(256)
void k_node3(const float* __restrict__ h2,
             const float* __restrict__ Wrel, const float* __restrict__ b,
             const float* __restrict__ Wroot,
             float* __restrict__ z, float* __restrict__ out, int N) {
    int i = blockIdx.x * 256 + threadIdx.x;
    if (i >= N) return;
    float zr[3] = {0.f, 0.f, 0.f};
    float zo[3] = {b[0], b[1], b[2]};
    const float4* h4 = reinterpret_cast<const float4*>(h2 + (size_t)i * HIDDEN);
    for (int kk = 0; kk < HIDDEN / 4; ++kk) {
        float4 hv = h4[kk];
#pragma unroll
        for (int j = 0; j < 4; ++j) {
            int k = kk * 4 + j;
            float hj = (j == 0) ? hv.x : (j == 1) ? hv.y : (j == 2) ? hv.z : hv.w;
#pragma unroll
            for (int c = 0; c < 3; ++c) {
                zr[c] = fmaf(hj, Wrel [k * 3 + c], zr[c]);
                zo[c] = fmaf(hj, Wroot[k * 3 + c], zo[c]);
            }
        }
    }
    z[(size_t)i * 3 + 0] = zr[0]; z[(size_t)i * 3 + 1] = zr[1]; z[(size_t)i * 3 + 2] = zr[2];
    out[(size_t)i * 3 + 0] = zo[0]; out[(size_t)i * 3 + 1] = zo[1]; out[(size_t)i * 3 + 2] = zo[2];
}

__global__ __launch_bounds__(256)
void k_gather3(const int* __restrict__ offs, const int2* __restrict__ cpack,
               const float* __restrict__ z, float* __restrict__ out,
               int N, int E) {
    int i = blockIdx.x * 256 + threadIdx.x;
    if (i >= N) return;
    int start = offs[i], end = end_of(offs, i, N, E);
    float a0 = 0.f, a1 = 0.f, a2 = 0.f;
    for (int j = start; j < end; ++j) {
        int2  p = cpack[j];
        int   s = p.x;
        float w = __int_as_float(p.y);
        const float* zp = z + (size_t)s * 3;
        a0 = fmaf(w, zp[0], a0);
        a1 = fmaf(w, zp[1], a1);
        a2 = fmaf(w, zp[2], a2);
    }
    out[(size_t)i * 3 + 0] += a0;
    out[(size_t)i * 3 + 1] += a1;
    out[(size_t)i * 3 + 2] += a2;
}

extern "C" void kernel_launch(void* const* d_in, const int* in_sizes, int n_in,
                              void* d_out, int out_size, void* d_ws, size_t ws_size,
                              hipStream_t stream) {
    const float* x      = (const float*)d_in[0];
    const int*   ei     = (const int*)  d_in[1];
    const float* ew     = (const float*)d_in[2];
    const float* W1rel  = (const float*)d_in[4];
    const float* b1     = (const float*)d_in[5];
    const float* W1root = (const float*)d_in[6];
    const float* W2rel  = (const float*)d_in[7];
    const float* b2     = (const float*)d_in[8];
    const float* W2root = (const float*)d_in[9];
    const float* W3rel  = (const float*)d_in[10];
    const float* b3     = (const float*)d_in[11];
    const float* W3root = (const float*)d_in[12];
    float* out = (float*)d_out;

    const int N = in_sizes[0] / 2;
    const int E = in_sizes[2];
    const int* src = ei;
    const int* dst = ei + E;

    // -------- workspace layout --------
    // h     : N*128 f32   (h1, overwritten in place by h2; front E ints alias
    //         rank during CSR build — rank dead before gatherfused writes h)
    // aggr  : N*128 f32   (layer-2 aggregation; front N*3 reused for z)
    // offs  : N int | bsum : SCAN_B int
    // cpack : E int2      (front N ints alias cnt — cnt dead before k_fill)
    // yv    : N float4    (combined (aggr1,x) per node, L2-resident)
    float* h    = (float*)d_ws;
    float* aggr = h + (size_t)N * HIDDEN;
    int*   offs = (int*)(aggr + (size_t)N * HIDDEN);
    int*   bsum = offs + N;
    size_t cpo  = (size_t)(bsum + SCAN_B - (int*)d_ws);
    cpo = (cpo + 1) & ~(size_t)1;          // 8B alignment
    int2*   cpack = (int2*)((int*)d_ws + cpo);
    size_t yvo  = (size_t)((char*)(cpack + E) - (char*)d_ws);
    yvo = (yvo + 15) & ~(size_t)15;        // 16B alignment
    float4* yv  = (float4*)((char*)d_ws + yvo);
    int* cnt  = (int*)cpack;               // alias: dead before k_fill writes cpack
    int* rank = (int*)h;                   // alias: dead before gatherfused writes h

    const int nbScan = (N + SCAN_B - 1) / SCAN_B;

    // -------- CSR build --------
    hipMemsetAsync(cnt, 0, (size_t)N * sizeof(int), stream);
    k_hist <<<(E + 255) / 256, 256, 0, stream>>>(dst, cnt, rank, E);
    k_scan1<<<nbScan, SCAN_B, 0, stream>>>(cnt, offs, bsum, N);
    k_scan2<<<1, SCAN_B, 0, stream>>>(bsum, nbScan);
    k_scan3<<<nbScan, SCAN_B, 0, stream>>>(offs, bsum, N);
    k_fill <<<(E + 255) / 256, 256, 0, stream>>>(src, dst, ew, offs, rank, cpack, E);

    // -------- layer 1 aggregation (2ch) + y pack --------
    k_gather2<<<(N + 255) / 256, 256, 0, stream>>>(offs, cpack, x, yv, N, E);

    // -------- fused layer-2 aggregation + layer-1 node update --------
    {
        long long threads = (long long)N * 64;
        k_gatherfused<<<(int)((threads + 255) / 256), 256, 0, stream>>>(
            offs, cpack, yv, W1rel, b1, W1root, h, aggr, N, E);
    }

    // -------- layer 2 node update --------
    k_node2<<<(N + BM2 - 1) / BM2, 256, 0, stream>>>(aggr, h, W2rel, b2, W2root, N);

    // -------- layer 3 --------
    float* z = aggr;   // aggr dead after node2; reuse front N*3 for z
    k_node3  <<<(N + 255) / 256, 256, 0, stream>>>(h, W3rel, b3, W3root, z, out, N);
    k_gather3<<<(N + 255) / 256, 256, 0, stream>>>(offs, cpack, z, out, N, E);
}